// Round 7
// baseline (377.554 us; speedup 1.0000x reference)
//
#include <hip/hip_runtime.h>

// FAVOR+ attention, B=8 H=4 L=4096 D=128 M=640, fp32 in/out.
// out = (phi_q @ ctx) / (phi_q @ ksum); exp(eps)/sqrt(M) and per-row e^{-g_q}
// cancel in the ratio. Only g_k kept (fp16).
// R9: k1 m-chunk 128->64: LDS 71->36.4 KB, acc halved -> launch_bounds(256,3);
// grid rebalanced to 2 L-parts x 10 m-chunks = 640 blocks, ALL co-resident
// (3/CU*256=768 slots, no tail). ksum pass re-split 4 threads/row (qq*32)
// to cut its 8-way bank conflict to ~4-way. 2 ctx partials -> k_cvt halves.
// k2 = R8 verbatim (LDS-fed MFMA operands, dbuf sProj staging) except
// 2-partial ksum sum.
// (R9 resubmit #2: two consecutive GPUAcquisitionTimeouts, no data yet.)

#define BH 32
#define LSEQ 4096
#define DIM 128
#define MFEAT 640
#define LDSW 136   // k1 padded row stride (elements); 272 B rows
#define LDSW2 72   // k2 padded row stride for 64-wide sPhi; 144 B rows

typedef __bf16 bf16x8 __attribute__((ext_vector_type(8)));
typedef float f32x4 __attribute__((ext_vector_type(4)));

__device__ __forceinline__ unsigned short f2b(float f) {
    union { float f; unsigned u; } c; c.f = f;
    unsigned u = c.u + 0x7FFFu + ((c.u >> 16) & 1u);   // RNE bf16 (finite inputs only)
    return (unsigned short)(u >> 16);
}
__device__ __forceinline__ float b2f(unsigned short h) {
    union { unsigned u; float f; } c; c.u = ((unsigned)h) << 16;
    return c.f;
}
__device__ __forceinline__ unsigned short f2h(float f) {
    union { _Float16 h; unsigned short u; } c; c.h = (_Float16)f; return c.u;
}
__device__ __forceinline__ float h2f(unsigned short u) {
    union { unsigned short u; _Float16 h; } c; c.u = u; return (float)c.h;
}
__device__ __forceinline__ bf16x8 ld8(const unsigned short* p) {
    union { uint4 q; bf16x8 v; } c;
    c.q = *reinterpret_cast<const uint4*>(p);
    return c.v;
}
// async global->LDS, 16 B per lane; LDS dest = uniform base + lane*16
__device__ __forceinline__ void gl_lds16(const unsigned short* g, unsigned short* l) {
    __builtin_amdgcn_global_load_lds(
        (const __attribute__((address_space(1))) void*)g,
        (__attribute__((address_space(3))) void*)l, 16, 0, 0);
}

// ---------------- prep: rows of 128, optional scale + g = 0.5*sum((x*s)^2) (fp16) -----------
__global__ void prep_rows(const float* __restrict__ src, unsigned short* __restrict__ dst,
                          unsigned short* __restrict__ gout, int nrows, float scale)
{
    const int row = blockIdx.x * 8 + (threadIdx.x >> 5);
    const int ln = threadIdx.x & 31;
    if (row >= nrows) return;
    const float4 f = *reinterpret_cast<const float4*>(src + (size_t)row * DIM + ln * 4);
    const float a = f.x * scale, b = f.y * scale, c = f.z * scale, d = f.w * scale;
    ushort4 o; o.x = f2b(a); o.y = f2b(b); o.z = f2b(c); o.w = f2b(d);
    *reinterpret_cast<ushort4*>(dst + (size_t)row * DIM + ln * 4) = o;
    if (gout != nullptr) {
        float ss = a * a + b * b + c * c + d * d;
        #pragma unroll
        for (int off = 16; off >= 1; off >>= 1) ss += __shfl_xor(ss, off, 64);
        if (ln == 0) gout[row] = f2h(0.5f * ss);
    }
}

// ---------------- prep: v [bh][l][e] fp32 -> vt [bh][e][l] bf16 ----------------
__global__ void prep_vt_k(const float* __restrict__ v, unsigned short* __restrict__ vt)
{
    __shared__ float tile[64][129];
    const int bh = blockIdx.x >> 6;
    const int l0 = (blockIdx.x & 63) * 64;
    const int tid = threadIdx.x;
    const float* vb = v + ((size_t)bh * LSEQ + l0) * DIM;
    for (int u = tid; u < 2048; u += 256) {
        const int r = u >> 5, c = (u & 31) * 4;
        const float4 f = *reinterpret_cast<const float4*>(vb + (size_t)r * DIM + c);
        tile[r][c] = f.x; tile[r][c + 1] = f.y; tile[r][c + 2] = f.z; tile[r][c + 3] = f.w;
    }
    __syncthreads();
    const int e = tid >> 1, hf = tid & 1;
    unsigned w[16];
    #pragma unroll
    for (int j = 0; j < 16; ++j) {
        w[j] = ((unsigned)f2b(tile[hf * 32 + 2 * j][e])) |
               (((unsigned)f2b(tile[hf * 32 + 2 * j + 1][e])) << 16);
    }
    unsigned short* dst = vt + ((size_t)bh * DIM + e) * LSEQ + l0 + hf * 32;
    uint4* d4 = reinterpret_cast<uint4*>(dst);
    d4[0] = make_uint4(w[0], w[1], w[2], w[3]);
    d4[1] = make_uint4(w[4], w[5], w[6], w[7]);
    d4[2] = make_uint4(w[8], w[9], w[10], w[11]);
    d4[3] = make_uint4(w[12], w[13], w[14], w[15]);
}

// ---------------- kernel 1: per-part ctx partials [part][bh][e][m] + ksum4 ----------------
// MODE 0: fp32 partials; MODE 1: bf16 partials (ws-constrained fallback)
// m-chunk 64, 2 L-parts (2048 l each, 16 tiles). LDS 36.4 KB, 3 blocks/CU,
// all 640 blocks co-resident.
template<int MODE>
__global__ __launch_bounds__(256, 3) void k1_ctx(
    const unsigned short* __restrict__ kb, const unsigned short* __restrict__ gk,
    const unsigned short* __restrict__ projb, const unsigned short* __restrict__ vt,
    void* __restrict__ ctx4, float* __restrict__ ksum4)
{
    __shared__ __align__(16) unsigned short sProj[64 * LDSW];
    __shared__ __align__(16) unsigned short sPhi[64 * LDSW];   // [m][l]
    __shared__ float sG[128];
    __shared__ float sKred[256];

    const int tid = threadIdx.x;
    const int wave = tid >> 6, lane = tid & 63;
    const int quad = lane >> 4, lx = lane & 15;

    // XCD swizzle: same-bh blocks land on same XCD
    const int xcd = blockIdx.x & 7;
    const int kk = blockIdx.x >> 3;           // 0..79
    const int bh = xcd * 4 + kk / 20;
    const int t20 = kk % 20;
    const int part = t20 / 10;                // L split 0..1 (2048 rows each)
    const int mc = t20 % 10;                  // m-chunk 0..9 (64 each)
    const int m0 = mc * 64;
    const int lbase = part * 2048;

    // stage proj chunk once per block (64 rows x 128)
    for (int u = tid; u < 64 * 16; u += 256) {
        const int r = u >> 4, c = (u & 15) * 8;
        *reinterpret_cast<uint4*>(&sProj[r * LDSW + c]) =
            *reinterpret_cast<const uint4*>(projb + (size_t)(m0 + r) * DIM + c);
    }

    f32x4 acc[4][2];
    #pragma unroll
    for (int i = 0; i < 4; ++i)
        #pragma unroll
        for (int j = 0; j < 2; ++j) acc[i][j] = f32x4{0.f, 0.f, 0.f, 0.f};
    float ksacc = 0.f;

    const unsigned short* kbase = kb + (size_t)bh * (LSEQ * DIM);
    const unsigned short* vbase = vt + (size_t)bh * (DIM * LSEQ);
    const unsigned short* gbase = gk + (size_t)bh * LSEQ;

    #pragma unroll 1
    for (int tile = 0; tile < 16; ++tile) {
        const int l0 = lbase + tile * 128;
        if (tid < 128) sG[tid] = h2f(gbase[l0 + tid]);

        // k A-frags for this tile (wave owns 32 l-rows)
        bf16x8 afr[2][4];
        #pragma unroll
        for (int lt = 0; lt < 2; ++lt)
            #pragma unroll
            for (int ks = 0; ks < 4; ++ks)
                afr[lt][ks] = ld8(kbase + (size_t)(l0 + wave * 32 + lt * 16 + lx) * DIM + ks * 32 + quad * 8);

        __syncthreads();   // prev tile's sPhi readers done; sG (and sProj on t0) visible

        // MFMA1 split by lt: 4 chains each half; proj from LDS
        #pragma unroll
        for (int lt = 0; lt < 2; ++lt) {
            f32x4 S[4];
            #pragma unroll
            for (int mt = 0; mt < 4; ++mt) S[mt] = f32x4{0.f, 0.f, 0.f, 0.f};
            #pragma unroll
            for (int ks = 0; ks < 4; ++ks)
                #pragma unroll
                for (int mt = 0; mt < 4; ++mt) {
                    const bf16x8 pfr = ld8(&sProj[(mt * 16 + lx) * LDSW + ks * 32 + quad * 8]);
                    S[mt] = __builtin_amdgcn_mfma_f32_16x16x32_bf16(afr[lt][ks], pfr, S[mt], 0, 0, 0);
                }
            const float4 g = *reinterpret_cast<const float4*>(&sG[wave * 32 + lt * 16 + quad * 4]);
            #pragma unroll
            for (int mt = 0; mt < 4; ++mt) {
                ushort4 h;
                h.x = f2b(__expf(S[mt][0] - g.x)); h.y = f2b(__expf(S[mt][1] - g.y));
                h.z = f2b(__expf(S[mt][2] - g.z)); h.w = f2b(__expf(S[mt][3] - g.w));
                *reinterpret_cast<ushort4*>(&sPhi[(mt * 16 + lx) * LDSW + wave * 32 + lt * 16 + quad * 4]) = h;
            }
        }
        __syncthreads();

        // vt B-frags issued early (L2 latency covered by ksum-partial VALU below)
        bf16x8 vfr0[4], vfr1[4];
        #pragma unroll
        for (int ks = 0; ks < 4; ++ks) {
            vfr0[ks] = ld8(vbase + (size_t)(wave * 32 + lx) * LSEQ + l0 + ks * 32 + quad * 8);
            vfr1[ks] = ld8(vbase + (size_t)(wave * 32 + 16 + lx) * LSEQ + l0 + ks * 32 + quad * 8);
        }
        // ksum partial: 4 threads per m-row, 32 l each (less bank aliasing)
        {
            const int ml = tid >> 2, qq = tid & 3;
            const uint4* prow = reinterpret_cast<const uint4*>(&sPhi[ml * LDSW + qq * 32]);
            float s = 0.f;
            #pragma unroll
            for (int j = 0; j < 4; ++j) {
                const uint4 ph = prow[j];
                s += b2f((unsigned short)(ph.x & 0xffff)) + b2f((unsigned short)(ph.x >> 16))
                   + b2f((unsigned short)(ph.y & 0xffff)) + b2f((unsigned short)(ph.y >> 16))
                   + b2f((unsigned short)(ph.z & 0xffff)) + b2f((unsigned short)(ph.z >> 16))
                   + b2f((unsigned short)(ph.w & 0xffff)) + b2f((unsigned short)(ph.w >> 16));
            }
            ksacc += s;
        }
        // MFMA2: ctx[m(64), e(32/wave)] += phi^T . v  (8 independent chains)
        #pragma unroll
        for (int ks = 0; ks < 4; ++ks) {
            #pragma unroll
            for (int mt = 0; mt < 4; ++mt) {
                const bf16x8 afr2 = ld8(&sPhi[(mt * 16 + lx) * LDSW + ks * 32 + quad * 8]);
                acc[mt][0] = __builtin_amdgcn_mfma_f32_16x16x32_bf16(afr2, vfr0[ks], acc[mt][0], 0, 0, 0);
                acc[mt][1] = __builtin_amdgcn_mfma_f32_16x16x32_bf16(afr2, vfr1[ks], acc[mt][1], 0, 0, 0);
            }
        }
    }

    // plain transposed stores: ctx4[part][bh][e][m]; lane holds 4 consecutive m
    #pragma unroll
    for (int mt = 0; mt < 4; ++mt)
        #pragma unroll
        for (int j = 0; j < 2; ++j) {
            const int e = wave * 32 + j * 16 + lx;
            const size_t off = (((size_t)part * BH + bh) * DIM + e) * MFEAT + m0 + mt * 16 + quad * 4;
            if (MODE == 0) {
                float4 st; st.x = acc[mt][j][0]; st.y = acc[mt][j][1]; st.z = acc[mt][j][2]; st.w = acc[mt][j][3];
                *reinterpret_cast<float4*>((float*)ctx4 + off) = st;
            } else {
                ushort4 st; st.x = f2b(acc[mt][j][0]); st.y = f2b(acc[mt][j][1]);
                st.z = f2b(acc[mt][j][2]); st.w = f2b(acc[mt][j][3]);
                *reinterpret_cast<ushort4*>((unsigned short*)ctx4 + off) = st;
            }
        }
    sKred[tid] = ksacc;
    __syncthreads();
    if (tid < 64)
        ksum4[((size_t)part * BH + bh) * MFEAT + m0 + tid] =
            sKred[4 * tid] + sKred[4 * tid + 1] + sKred[4 * tid + 2] + sKred[4 * tid + 3];
}

// ---------------- cvt: sum 2 partials -> ctxb bf16 [bh][e][m] (elementwise) ----------------
#define PELEM (size_t)(BH * DIM * MFEAT)   // 2,621,440 per partial
template<int MODE>
__global__ void k_cvt(const float* __restrict__ pf, const unsigned short* __restrict__ ph,
                      unsigned short* __restrict__ ctxb)
{
    const size_t base = ((size_t)blockIdx.x * 256 + threadIdx.x) * 4;
    float s0, s1, s2, s3;
    if (MODE == 0) {
        float4 a = *reinterpret_cast<const float4*>(pf + base);
        float4 b = *reinterpret_cast<const float4*>(pf + PELEM + base);
        s0 = a.x + b.x; s1 = a.y + b.y;
        s2 = a.z + b.z; s3 = a.w + b.w;
    } else {
        ushort4 a = *reinterpret_cast<const ushort4*>(ph + base);
        ushort4 b = *reinterpret_cast<const ushort4*>(ph + PELEM + base);
        s0 = b2f(a.x) + b2f(b.x);
        s1 = b2f(a.y) + b2f(b.y);
        s2 = b2f(a.z) + b2f(b.z);
        s3 = b2f(a.w) + b2f(b.w);
    }
    ushort4 o; o.x = f2b(s0); o.y = f2b(s1); o.z = f2b(s2); o.w = f2b(s3);
    *reinterpret_cast<ushort4*>(ctxb + base) = o;   // MODE 1: in-place over partial 0 (own slot)
}

// ---------------- kernel 2: out = (phi_q @ ctx) / (phi_q @ ksum) ----------------
// 128-row tiles, grid 1024, XCD swizzle. m-chunk 64. ALL MFMA operands LDS-fed:
// sProj double-buffered (stage ch+1 during ch), sCtx single-buffered (staged
// during MFMA1, consumed after barrier B). Granule-XOR swizzle on both.
__global__ __launch_bounds__(256, 2) void k2_out(
    const float* __restrict__ q, const unsigned short* __restrict__ projb,
    const unsigned short* __restrict__ ctxb, const float* __restrict__ ksum4,
    float* __restrict__ out, float scale)
{
    __shared__ __align__(16) unsigned short sPhi[128 * LDSW2];   // [l][m] padded
    __shared__ __align__(16) unsigned short sCtx[128 * 64];      // swizzled [e][g^e]
    __shared__ __align__(16) unsigned short sProj[2][64 * DIM];  // dbuf swizzled [m][g^m]
    __shared__ float sKs[MFEAT];
    __shared__ float sDred[256];

    const int tid = threadIdx.x;
    const int wave = tid >> 6, lane = tid & 63;
    const int quad = lane >> 4, lx = lane & 15;

    // XCD swizzle: 32 blocks per bh share one XCD (ctxb[bh] stays L2-hot)
    const int xcd = blockIdx.x & 7;
    const int kk = blockIdx.x >> 3;           // 0..127
    const int bh = xcd * 4 + (kk >> 5);
    const int l0 = (kk & 31) * 128;

    // prologue: stage proj chunk 0 (async; drained by first barrier)
    {
        const int j = lane & 15;
        #pragma unroll
        for (int i = 0; i < 4; ++i) {
            const int r = wave * 16 + i * 4 + (lane >> 4);
            const int g = j ^ (r & 15);
            gl_lds16(projb + (size_t)r * DIM + g * 8,
                     &sProj[0][(wave * 16 + i * 4) * DIM]);
        }
    }

    for (int i = tid; i < MFEAT; i += 256)
        sKs[i] = ksum4[(size_t)bh * MFEAT + i]
               + ksum4[(size_t)(BH + bh) * MFEAT + i];

    // q frags: fp32 -> scaled bf16 in-reg (32 VGPR), B-operand of swapped MFMA1
    bf16x8 qa[2][4];
    #pragma unroll
    for (int lt = 0; lt < 2; ++lt)
        #pragma unroll
        for (int ks = 0; ks < 4; ++ks) {
            const float* p = q + ((size_t)bh * LSEQ + l0 + wave * 32 + lt * 16 + lx) * DIM + ks * 32 + quad * 8;
            const float4 f0 = *reinterpret_cast<const float4*>(p);
            const float4 f1 = *reinterpret_cast<const float4*>(p + 4);
            union { unsigned u[4]; bf16x8 v; } c;
            c.u[0] = ((unsigned)f2b(f0.x * scale)) | (((unsigned)f2b(f0.y * scale)) << 16);
            c.u[1] = ((unsigned)f2b(f0.z * scale)) | (((unsigned)f2b(f0.w * scale)) << 16);
            c.u[2] = ((unsigned)f2b(f1.x * scale)) | (((unsigned)f2b(f1.y * scale)) << 16);
            c.u[3] = ((unsigned)f2b(f1.z * scale)) | (((unsigned)f2b(f1.w * scale)) << 16);
            qa[lt][ks] = c.v;
        }

    f32x4 oacc[2][8];
    #pragma unroll
    for (int i = 0; i < 2; ++i)
        #pragma unroll
        for (int j = 0; j < 8; ++j) oacc[i][j] = f32x4{0.f, 0.f, 0.f, 0.f};
    float dacc = 0.f;

    const unsigned short* cbase = ctxb + (size_t)bh * DIM * MFEAT;

    #pragma unroll 1
    for (int ch = 0; ch < 10; ++ch) {
        const int m0 = ch * 64;
        const unsigned short* pcur = sProj[ch & 1];
        __syncthreads();   // prev readers done; drains staging -> sProj[cur] ready

        // async-stage ctx tile [128 e][64 m] for THIS chunk (consumed after barrier B)
        {
            const int jj = lane & 7;
            const int rsub = lane >> 3;
            #pragma unroll
            for (int i = 0; i < 4; ++i) {
                const int r = wave * 32 + i * 8 + rsub;
                const int g = jj ^ (r & 7);
                gl_lds16(cbase + (size_t)r * MFEAT + m0 + g * 8,
                         &sCtx[(wave * 32 + i * 8) * 64]);
            }
        }
        // async-stage proj chunk ch+1 into the other buffer (consumed next iter)
        if (ch < 9) {
            unsigned short* pnxt = sProj[(ch & 1) ^ 1];
            const int j = lane & 15;
            #pragma unroll
            for (int i = 0; i < 4; ++i) {
                const int r = wave * 16 + i * 4 + (lane >> 4);
                const int g = j ^ (r & 15);
                gl_lds16(projb + (size_t)(m0 + 64 + r) * DIM + g * 8,
                         &pnxt[(wave * 16 + i * 4) * DIM]);
            }
        }

        // swapped MFMA1: S'[m, l] = proj . q^T ; proj A-frags from swizzled LDS
        #pragma unroll
        for (int lt = 0; lt < 2; ++lt) {
            f32x4 S[4];
            #pragma unroll
            for (int mt = 0; mt < 4; ++mt) S[mt] = f32x4{0.f, 0.f, 0.f, 0.f};
            #pragma unroll
            for (int ks = 0; ks < 4; ++ks)
                #pragma unroll
                for (int mt = 0; mt < 4; ++mt) {
                    const bf16x8 pa = ld8(&pcur[(mt * 16 + lx) * DIM + (((ks * 4 + quad) ^ lx) * 8)]);
                    S[mt] = __builtin_amdgcn_mfma_f32_16x16x32_bf16(pa, qa[lt][ks], S[mt], 0, 0, 0);
                }
            #pragma unroll
            for (int mt = 0; mt < 4; ++mt) {
                ushort4 h;
                h.x = f2b(__expf(S[mt][0])); h.y = f2b(__expf(S[mt][1]));
                h.z = f2b(__expf(S[mt][2])); h.w = f2b(__expf(S[mt][3]));
                *reinterpret_cast<ushort4*>(&sPhi[(wave * 32 + lt * 16 + lx) * LDSW2 + mt * 16 + quad * 4]) = h;
            }
        }
        __syncthreads();   // sPhi visible; drains vmcnt -> sCtx + next sProj ready

        // D partial: 2 threads per l-row, 32 m each; same bf16 phi as numerator
        {
            const int row = tid >> 1, hf = tid & 1;
            const uint4* prow = reinterpret_cast<const uint4*>(&sPhi[row * LDSW2 + hf * 32]);
            const float4* kp = reinterpret_cast<const float4*>(&sKs[m0 + hf * 32]);
            float s = 0.f;
            #pragma unroll
            for (int j = 0; j < 4; ++j) {
                const uint4 ph = prow[j];
                const float4 ka = kp[2 * j];
                const float4 kb2 = kp[2 * j + 1];
                s += b2f((unsigned short)(ph.x & 0xffff)) * ka.x + b2f((unsigned short)(ph.x >> 16)) * ka.y
                   + b2f((unsigned short)(ph.y & 0xffff)) * ka.z + b2f((unsigned short)(ph.y >> 16)) * ka.w
                   + b2f((unsigned short)(ph.z & 0xffff)) * kb2.x + b2f((unsigned short)(ph.z >> 16)) * kb2.y
                   + b2f((unsigned short)(ph.w & 0xffff)) * kb2.z + b2f((unsigned short)(ph.w >> 16)) * kb2.w;
            }
            dacc += s;
        }
        // MFMA2: out[l(32/wave), e(128)] += phi_q . ctx ; B-frags from swizzled sCtx
        #pragma unroll
        for (int ks = 0; ks < 2; ++ks) {
            const bf16x8 pa0 = ld8(&sPhi[(wave * 32 + lx) * LDSW2 + ks * 32 + quad * 8]);
            const bf16x8 pa1 = ld8(&sPhi[(wave * 32 + 16 + lx) * LDSW2 + ks * 32 + quad * 8]);
            #pragma unroll
            for (int et = 0; et < 8; ++et) {
                const bf16x8 cb = ld8(&sCtx[(et * 16 + lx) * 64 + (((ks * 4 + quad) ^ (lx & 7)) * 8)]);
                oacc[0][et] = __builtin_amdgcn_mfma_f32_16x16x32_bf16(pa0, cb, oacc[0][et], 0, 0, 0);
                oacc[1][et] = __builtin_amdgcn_mfma_f32_16x16x32_bf16(pa1, cb, oacc[1][et], 0, 0, 0);
            }
        }
    }

    sDred[tid] = dacc;
    __syncthreads();
    #pragma unroll
    for (int lt = 0; lt < 2; ++lt)
        #pragma unroll
        for (int r = 0; r < 4; ++r) {
            const int lrow = wave * 32 + lt * 16 + quad * 4 + r;
            const float Dv = sDred[2 * lrow] + sDred[2 * lrow + 1];
            const float inv = 1.0f / Dv;
            float* ob = out + ((size_t)bh * LSEQ + l0 + lrow) * DIM;
            #pragma unroll
            for (int et = 0; et < 8; ++et)
                ob[et * 16 + lx] = oacc[lt][et][r] * inv;
        }
}

extern "C" void kernel_launch(void* const* d_in, const int* in_sizes, int n_in,
                              void* d_out, int out_size, void* d_ws, size_t ws_size,
                              hipStream_t stream)
{
    (void)in_sizes; (void)n_in; (void)out_size;
    const float* q = (const float*)d_in[0];
    const float* k = (const float*)d_in[1];
    const float* v = (const float*)d_in[2];
    const float* proj = (const float*)d_in[3];
    float* out = (float*)d_out;
    char* ws = (char*)d_ws;

    // ws layout (bytes):
    //   kb     @ 0          33,554,432
    //   vt     @ 33,554,432 33,554,432   (dead after k1; ctxb aliases here in MODE 0)
    //   projb  @ 67,108,864    163,840
    //   gk     @ 67,272,704    262,144   (fp16)
    //   ksum4  @ 67,534,848    163,840   (2 partials now)
    //   ctx4   @ 67,862,528  20,971,520 fp32 x2 (MODE 0) | 10,485,760 bf16 x2 (MODE 1)
    unsigned short* kb    = (unsigned short*)(ws);
    unsigned short* vt    = (unsigned short*)(ws + 33554432);
    unsigned short* projb = (unsigned short*)(ws + 67108864);
    unsigned short* gk    = (unsigned short*)(ws + 67272704);
    float*          ksum4 = (float*)         (ws + 67534848);
    char*           ctx4  = ws + 67862528;

    const bool modeA = (ws_size >= 88834048u);   // fp32 2-partials fit?
    unsigned short* ctxb = modeA ? (unsigned short*)(ws + 33554432)   // alias over dead vt
                                 : (unsigned short*)ctx4;             // in-place over partial 0

    const float s = 0.2973017787506803f;  // 1/128^0.25

    prep_rows<<<16384, 256, 0, stream>>>(k, kb, gk, BH * LSEQ, s);
    prep_rows<<<80, 256, 0, stream>>>(proj, projb, nullptr, MFEAT, 1.0f);
    prep_vt_k<<<BH * 64, 256, 0, stream>>>(v, vt);
    if (modeA) {
        k1_ctx<0><<<640, 256, 0, stream>>>(kb, gk, projb, vt, ctx4, ksum4);
        k_cvt<0><<<2560, 256, 0, stream>>>((const float*)ctx4, nullptr, ctxb);
    } else {
        k1_ctx<1><<<640, 256, 0, stream>>>(kb, gk, projb, vt, ctx4, ksum4);
        k_cvt<1><<<2560, 256, 0, stream>>>(nullptr, (const unsigned short*)ctx4, ctxb);
    }
    k2_out<<<1024, 256, 0, stream>>>(q, projb, ctxb, ksum4, out, s);
}

// Round 8
// 364.937 us; speedup vs baseline: 1.0346x; 1.0346x over previous
//
#include <hip/hip_runtime.h>

// FAVOR+ attention, B=8 H=4 L=4096 D=128 M=640, fp32 in/out.
// out = (phi_q @ ctx) / (phi_q @ ksum); exp(eps)/sqrt(M) and per-row e^{-g_q}
// cancel in the ratio. Only g_k kept (fp16).
// R10: k1/k2 are LDS-pipe-bound (R9: +occupancy didn't help, conflicts
// identical). Cut LDS ops per work unit on R8 geometry:
//  k1: pfr shared across lt (64->32 reads/wave-tile); ksum accumulated in
//      registers during pack (kills 16-read ksum pass); vfr issued pre-barrier.
//  k2: pa shared across lt (32->16); D fused into pack from registers (kills
//      D-pass); sDred via shfl quad-reduce.
// Geometry = R8: k1 m-chunk 128, 4 L-parts, 4 fp32 partials; k2 m-chunk 64.

#define BH 32
#define LSEQ 4096
#define DIM 128
#define MFEAT 640
#define LDSW 136   // k1 padded row stride (elements); 272 B rows
#define LDSW2 72   // k2 padded row stride for 64-wide sPhi; 144 B rows

typedef __bf16 bf16x8 __attribute__((ext_vector_type(8)));
typedef float f32x4 __attribute__((ext_vector_type(4)));

__device__ __forceinline__ unsigned short f2b(float f) {
    union { float f; unsigned u; } c; c.f = f;
    unsigned u = c.u + 0x7FFFu + ((c.u >> 16) & 1u);   // RNE bf16 (finite inputs only)
    return (unsigned short)(u >> 16);
}
__device__ __forceinline__ float b2f(unsigned short h) {
    union { unsigned u; float f; } c; c.u = ((unsigned)h) << 16;
    return c.f;
}
__device__ __forceinline__ unsigned short f2h(float f) {
    union { _Float16 h; unsigned short u; } c; c.h = (_Float16)f; return c.u;
}
__device__ __forceinline__ float h2f(unsigned short u) {
    union { unsigned short u; _Float16 h; } c; c.u = u; return (float)c.h;
}
__device__ __forceinline__ bf16x8 ld8(const unsigned short* p) {
    union { uint4 q; bf16x8 v; } c;
    c.q = *reinterpret_cast<const uint4*>(p);
    return c.v;
}
// async global->LDS, 16 B per lane; LDS dest = uniform base + lane*16
__device__ __forceinline__ void gl_lds16(const unsigned short* g, unsigned short* l) {
    __builtin_amdgcn_global_load_lds(
        (const __attribute__((address_space(1))) void*)g,
        (__attribute__((address_space(3))) void*)l, 16, 0, 0);
}

// ---------------- prep: rows of 128, optional scale + g = 0.5*sum((x*s)^2) (fp16) -----------
__global__ void prep_rows(const float* __restrict__ src, unsigned short* __restrict__ dst,
                          unsigned short* __restrict__ gout, int nrows, float scale)
{
    const int row = blockIdx.x * 8 + (threadIdx.x >> 5);
    const int ln = threadIdx.x & 31;
    if (row >= nrows) return;
    const float4 f = *reinterpret_cast<const float4*>(src + (size_t)row * DIM + ln * 4);
    const float a = f.x * scale, b = f.y * scale, c = f.z * scale, d = f.w * scale;
    ushort4 o; o.x = f2b(a); o.y = f2b(b); o.z = f2b(c); o.w = f2b(d);
    *reinterpret_cast<ushort4*>(dst + (size_t)row * DIM + ln * 4) = o;
    if (gout != nullptr) {
        float ss = a * a + b * b + c * c + d * d;
        #pragma unroll
        for (int off = 16; off >= 1; off >>= 1) ss += __shfl_xor(ss, off, 64);
        if (ln == 0) gout[row] = f2h(0.5f * ss);
    }
}

// ---------------- prep: v [bh][l][e] fp32 -> vt [bh][e][l] bf16 ----------------
__global__ void prep_vt_k(const float* __restrict__ v, unsigned short* __restrict__ vt)
{
    __shared__ float tile[64][129];
    const int bh = blockIdx.x >> 6;
    const int l0 = (blockIdx.x & 63) * 64;
    const int tid = threadIdx.x;
    const float* vb = v + ((size_t)bh * LSEQ + l0) * DIM;
    for (int u = tid; u < 2048; u += 256) {
        const int r = u >> 5, c = (u & 31) * 4;
        const float4 f = *reinterpret_cast<const float4*>(vb + (size_t)r * DIM + c);
        tile[r][c] = f.x; tile[r][c + 1] = f.y; tile[r][c + 2] = f.z; tile[r][c + 3] = f.w;
    }
    __syncthreads();
    const int e = tid >> 1, hf = tid & 1;
    unsigned w[16];
    #pragma unroll
    for (int j = 0; j < 16; ++j) {
        w[j] = ((unsigned)f2b(tile[hf * 32 + 2 * j][e])) |
               (((unsigned)f2b(tile[hf * 32 + 2 * j + 1][e])) << 16);
    }
    unsigned short* dst = vt + ((size_t)bh * DIM + e) * LSEQ + l0 + hf * 32;
    uint4* d4 = reinterpret_cast<uint4*>(dst);
    d4[0] = make_uint4(w[0], w[1], w[2], w[3]);
    d4[1] = make_uint4(w[4], w[5], w[6], w[7]);
    d4[2] = make_uint4(w[8], w[9], w[10], w[11]);
    d4[3] = make_uint4(w[12], w[13], w[14], w[15]);
}

// ---------------- kernel 1: per-part ctx partials [part][bh][e][m] + ksum4 ----------------
// MODE 0: fp32 partials; MODE 1: bf16 partials (ws-constrained fallback)
template<int MODE>
__global__ __launch_bounds__(256, 2) void k1_ctx(
    const unsigned short* __restrict__ kb, const unsigned short* __restrict__ gk,
    const unsigned short* __restrict__ projb, const unsigned short* __restrict__ vt,
    void* __restrict__ ctx4, float* __restrict__ ksum4)
{
    __shared__ __align__(16) unsigned short sProj[128 * LDSW];
    __shared__ __align__(16) unsigned short sPhi[128 * LDSW];  // [m][l]
    __shared__ float sG[128];
    __shared__ float sKred[512];

    const int tid = threadIdx.x;
    const int wave = tid >> 6, lane = tid & 63;
    const int quad = lane >> 4, lx = lane & 15;

    // XCD swizzle: same-bh blocks land on same XCD
    const int xcd = blockIdx.x & 7;
    const int kk = blockIdx.x >> 3;           // 0..79
    const int bh = xcd * 4 + kk / 20;
    const int t20 = kk % 20;
    const int part = t20 / 5;                 // L split 0..3
    const int mc = t20 % 5;                   // m-chunk 0..4 (128 each)
    const int m0 = mc * 128;
    const int lbase = part * 1024;

    // stage proj chunk once per block
    for (int u = tid; u < 128 * 16; u += 256) {
        const int r = u >> 4, c = (u & 15) * 8;
        *reinterpret_cast<uint4*>(&sProj[r * LDSW + c]) =
            *reinterpret_cast<const uint4*>(projb + (size_t)(m0 + r) * DIM + c);
    }

    f32x4 acc[8][2];
    #pragma unroll
    for (int i = 0; i < 8; ++i)
        #pragma unroll
        for (int j = 0; j < 2; ++j) acc[i][j] = f32x4{0.f, 0.f, 0.f, 0.f};
    float ksr[8];
    #pragma unroll
    for (int i = 0; i < 8; ++i) ksr[i] = 0.f;

    const unsigned short* kbase = kb + (size_t)bh * (LSEQ * DIM);
    const unsigned short* vbase = vt + (size_t)bh * (DIM * LSEQ);
    const unsigned short* gbase = gk + (size_t)bh * LSEQ;

    #pragma unroll 1
    for (int tile = 0; tile < 8; ++tile) {
        const int l0 = lbase + tile * 128;
        if (tid < 128) sG[tid] = h2f(gbase[l0 + tid]);

        // k A-frags for this tile (wave owns 32 l-rows)
        bf16x8 afr[2][4];
        #pragma unroll
        for (int lt = 0; lt < 2; ++lt)
            #pragma unroll
            for (int ks = 0; ks < 4; ++ks)
                afr[lt][ks] = ld8(kbase + (size_t)(l0 + wave * 32 + lt * 16 + lx) * DIM + ks * 32 + quad * 8);

        __syncthreads();   // prev tile's sPhi readers done; sG (and sProj on t0) visible

        // MFMA1: pfr shared across both lt -> 32 ds_read_b128 (was 64)
        f32x4 S0[8], S1[8];
        #pragma unroll
        for (int mt = 0; mt < 8; ++mt) { S0[mt] = f32x4{0.f,0.f,0.f,0.f}; S1[mt] = f32x4{0.f,0.f,0.f,0.f}; }
        #pragma unroll
        for (int ks = 0; ks < 4; ++ks)
            #pragma unroll
            for (int mt = 0; mt < 8; ++mt) {
                const bf16x8 pfr = ld8(&sProj[(mt * 16 + lx) * LDSW + ks * 32 + quad * 8]);
                S0[mt] = __builtin_amdgcn_mfma_f32_16x16x32_bf16(afr[0][ks], pfr, S0[mt], 0, 0, 0);
                S1[mt] = __builtin_amdgcn_mfma_f32_16x16x32_bf16(afr[1][ks], pfr, S1[mt], 0, 0, 0);
            }

        // exp + pack + register ksum (identical bf16 values as the MFMA consumes)
        {
            const float4 g0 = *reinterpret_cast<const float4*>(&sG[wave * 32 + quad * 4]);
            const float4 g1 = *reinterpret_cast<const float4*>(&sG[wave * 32 + 16 + quad * 4]);
            #pragma unroll
            for (int mt = 0; mt < 8; ++mt) {
                ushort4 h0;
                h0.x = f2b(__expf(S0[mt][0] - g0.x)); h0.y = f2b(__expf(S0[mt][1] - g0.y));
                h0.z = f2b(__expf(S0[mt][2] - g0.z)); h0.w = f2b(__expf(S0[mt][3] - g0.w));
                ksr[mt] += b2f(h0.x) + b2f(h0.y) + b2f(h0.z) + b2f(h0.w);
                *reinterpret_cast<ushort4*>(&sPhi[(mt * 16 + lx) * LDSW + wave * 32 + quad * 4]) = h0;
                ushort4 h1;
                h1.x = f2b(__expf(S1[mt][0] - g1.x)); h1.y = f2b(__expf(S1[mt][1] - g1.y));
                h1.z = f2b(__expf(S1[mt][2] - g1.z)); h1.w = f2b(__expf(S1[mt][3] - g1.w));
                ksr[mt] += b2f(h1.x) + b2f(h1.y) + b2f(h1.z) + b2f(h1.w);
                *reinterpret_cast<ushort4*>(&sPhi[(mt * 16 + lx) * LDSW + wave * 32 + 16 + quad * 4]) = h1;
            }
        }

        // vt B-frags issued BEFORE barrier: latency drains at the barrier,
        // covered by the pack-VALU above and other waves.
        bf16x8 vfr0[4], vfr1[4];
        #pragma unroll
        for (int ks = 0; ks < 4; ++ks) {
            vfr0[ks] = ld8(vbase + (size_t)(wave * 32 + lx) * LSEQ + l0 + ks * 32 + quad * 8);
            vfr1[ks] = ld8(vbase + (size_t)(wave * 32 + 16 + lx) * LSEQ + l0 + ks * 32 + quad * 8);
        }
        __syncthreads();   // sPhi visible; vfr drained

        // MFMA2: ctx[m(128), e(32/wave)] += phi^T . v  (16 independent chains)
        #pragma unroll
        for (int ks = 0; ks < 4; ++ks) {
            #pragma unroll
            for (int mt = 0; mt < 8; ++mt) {
                const bf16x8 afr2 = ld8(&sPhi[(mt * 16 + lx) * LDSW + ks * 32 + quad * 8]);
                acc[mt][0] = __builtin_amdgcn_mfma_f32_16x16x32_bf16(afr2, vfr0[ks], acc[mt][0], 0, 0, 0);
                acc[mt][1] = __builtin_amdgcn_mfma_f32_16x16x32_bf16(afr2, vfr1[ks], acc[mt][1], 0, 0, 0);
            }
        }
    }

    // plain transposed stores: ctx4[part][bh][e][m]; lane holds 4 consecutive m
    #pragma unroll
    for (int mt = 0; mt < 8; ++mt)
        #pragma unroll
        for (int j = 0; j < 2; ++j) {
            const int e = wave * 32 + j * 16 + lx;
            const size_t off = (((size_t)part * BH + bh) * DIM + e) * MFEAT + m0 + mt * 16 + quad * 4;
            if (MODE == 0) {
                float4 st; st.x = acc[mt][j][0]; st.y = acc[mt][j][1]; st.z = acc[mt][j][2]; st.w = acc[mt][j][3];
                *reinterpret_cast<float4*>((float*)ctx4 + off) = st;
            } else {
                ushort4 st; st.x = f2b(acc[mt][j][0]); st.y = f2b(acc[mt][j][1]);
                st.z = f2b(acc[mt][j][2]); st.w = f2b(acc[mt][j][3]);
                *reinterpret_cast<ushort4*>((unsigned short*)ctx4 + off) = st;
            }
        }

    // ksum: quad-reduce in-register, then cross-wave via small LDS
    #pragma unroll
    for (int mt = 0; mt < 8; ++mt) {
        ksr[mt] += __shfl_xor(ksr[mt], 16);
        ksr[mt] += __shfl_xor(ksr[mt], 32);
    }
    if (quad == 0) {
        #pragma unroll
        for (int mt = 0; mt < 8; ++mt)
            sKred[wave * 128 + mt * 16 + lx] = ksr[mt];
    }
    __syncthreads();
    if (tid < 128)
        ksum4[((size_t)part * BH + bh) * MFEAT + m0 + tid] =
            sKred[tid] + sKred[128 + tid] + sKred[256 + tid] + sKred[384 + tid];
}

// ---------------- cvt: sum 4 partials -> ctxb bf16 [bh][e][m] (elementwise) ----------------
#define PELEM (size_t)(BH * DIM * MFEAT)   // 2,621,440 per partial
template<int MODE>
__global__ void k_cvt(const float* __restrict__ pf, const unsigned short* __restrict__ ph,
                      unsigned short* __restrict__ ctxb)
{
    const size_t base = ((size_t)blockIdx.x * 256 + threadIdx.x) * 4;
    float s0, s1, s2, s3;
    if (MODE == 0) {
        float4 a = *reinterpret_cast<const float4*>(pf + base);
        float4 b = *reinterpret_cast<const float4*>(pf + PELEM + base);
        float4 c = *reinterpret_cast<const float4*>(pf + 2 * PELEM + base);
        float4 d = *reinterpret_cast<const float4*>(pf + 3 * PELEM + base);
        s0 = a.x + b.x + c.x + d.x; s1 = a.y + b.y + c.y + d.y;
        s2 = a.z + b.z + c.z + d.z; s3 = a.w + b.w + c.w + d.w;
    } else {
        ushort4 a = *reinterpret_cast<const ushort4*>(ph + base);
        ushort4 b = *reinterpret_cast<const ushort4*>(ph + PELEM + base);
        ushort4 c = *reinterpret_cast<const ushort4*>(ph + 2 * PELEM + base);
        ushort4 d = *reinterpret_cast<const ushort4*>(ph + 3 * PELEM + base);
        s0 = b2f(a.x) + b2f(b.x) + b2f(c.x) + b2f(d.x);
        s1 = b2f(a.y) + b2f(b.y) + b2f(c.y) + b2f(d.y);
        s2 = b2f(a.z) + b2f(b.z) + b2f(c.z) + b2f(d.z);
        s3 = b2f(a.w) + b2f(b.w) + b2f(c.w) + b2f(d.w);
    }
    ushort4 o; o.x = f2b(s0); o.y = f2b(s1); o.z = f2b(s2); o.w = f2b(s3);
    *reinterpret_cast<ushort4*>(ctxb + base) = o;   // MODE 1: in-place over partial 0 (own slot)
}

// ---------------- kernel 2: out = (phi_q @ ctx) / (phi_q @ ksum) ----------------
// 128-row tiles, grid 1024, XCD swizzle. m-chunk 64. ALL MFMA operands LDS-fed:
// sProj double-buffered, sCtx staged during MFMA1. pa shared across lt; D fused
// into the pack from registers (no separate D-pass).
__global__ __launch_bounds__(256, 2) void k2_out(
    const float* __restrict__ q, const unsigned short* __restrict__ projb,
    const unsigned short* __restrict__ ctxb, const float* __restrict__ ksum4,
    float* __restrict__ out, float scale)
{
    __shared__ __align__(16) unsigned short sPhi[128 * LDSW2];   // [l][m] padded
    __shared__ __align__(16) unsigned short sCtx[128 * 64];      // swizzled [e][g^e]
    __shared__ __align__(16) unsigned short sProj[2][64 * DIM];  // dbuf swizzled [m][g^m]
    __shared__ float sKs[MFEAT];
    __shared__ float sDred[128];

    const int tid = threadIdx.x;
    const int wave = tid >> 6, lane = tid & 63;
    const int quad = lane >> 4, lx = lane & 15;

    // XCD swizzle: 32 blocks per bh share one XCD (ctxb[bh] stays L2-hot)
    const int xcd = blockIdx.x & 7;
    const int kk = blockIdx.x >> 3;           // 0..127
    const int bh = xcd * 4 + (kk >> 5);
    const int l0 = (kk & 31) * 128;

    // prologue: stage proj chunk 0 (async; drained by first barrier)
    {
        const int j = lane & 15;
        #pragma unroll
        for (int i = 0; i < 4; ++i) {
            const int r = wave * 16 + i * 4 + (lane >> 4);
            const int g = j ^ (r & 15);
            gl_lds16(projb + (size_t)r * DIM + g * 8,
                     &sProj[0][(wave * 16 + i * 4) * DIM]);
        }
    }

    for (int i = tid; i < MFEAT; i += 256)
        sKs[i] = ksum4[(size_t)bh * MFEAT + i]
               + ksum4[(size_t)(BH + bh) * MFEAT + i]
               + ksum4[(size_t)(2 * BH + bh) * MFEAT + i]
               + ksum4[(size_t)(3 * BH + bh) * MFEAT + i];

    // q frags: fp32 -> scaled bf16 in-reg (32 VGPR), B-operand of swapped MFMA1
    bf16x8 qa[2][4];
    #pragma unroll
    for (int lt = 0; lt < 2; ++lt)
        #pragma unroll
        for (int ks = 0; ks < 4; ++ks) {
            const float* p = q + ((size_t)bh * LSEQ + l0 + wave * 32 + lt * 16 + lx) * DIM + ks * 32 + quad * 8;
            const float4 f0 = *reinterpret_cast<const float4*>(p);
            const float4 f1 = *reinterpret_cast<const float4*>(p + 4);
            union { unsigned u[4]; bf16x8 v; } c;
            c.u[0] = ((unsigned)f2b(f0.x * scale)) | (((unsigned)f2b(f0.y * scale)) << 16);
            c.u[1] = ((unsigned)f2b(f0.z * scale)) | (((unsigned)f2b(f0.w * scale)) << 16);
            c.u[2] = ((unsigned)f2b(f1.x * scale)) | (((unsigned)f2b(f1.y * scale)) << 16);
            c.u[3] = ((unsigned)f2b(f1.z * scale)) | (((unsigned)f2b(f1.w * scale)) << 16);
            qa[lt][ks] = c.v;
        }

    f32x4 oacc[2][8];
    #pragma unroll
    for (int i = 0; i < 2; ++i)
        #pragma unroll
        for (int j = 0; j < 8; ++j) oacc[i][j] = f32x4{0.f, 0.f, 0.f, 0.f};
    float d0 = 0.f, d1 = 0.f;

    const unsigned short* cbase = ctxb + (size_t)bh * DIM * MFEAT;

    #pragma unroll 1
    for (int ch = 0; ch < 10; ++ch) {
        const int m0 = ch * 64;
        const unsigned short* pcur = sProj[ch & 1];
        __syncthreads();   // prev readers done; drains staging -> sProj[cur] ready

        // async-stage ctx tile [128 e][64 m] for THIS chunk (consumed after barrier B)
        {
            const int jj = lane & 7;
            const int rsub = lane >> 3;
            #pragma unroll
            for (int i = 0; i < 4; ++i) {
                const int r = wave * 32 + i * 8 + rsub;
                const int g = jj ^ (r & 7);
                gl_lds16(cbase + (size_t)r * MFEAT + m0 + g * 8,
                         &sCtx[(wave * 32 + i * 8) * 64]);
            }
        }
        // async-stage proj chunk ch+1 into the other buffer (consumed next iter)
        if (ch < 9) {
            unsigned short* pnxt = sProj[(ch & 1) ^ 1];
            const int j = lane & 15;
            #pragma unroll
            for (int i = 0; i < 4; ++i) {
                const int r = wave * 16 + i * 4 + (lane >> 4);
                const int g = j ^ (r & 15);
                gl_lds16(projb + (size_t)(m0 + 64 + r) * DIM + g * 8,
                         &pnxt[(wave * 16 + i * 4) * DIM]);
            }
        }

        // swapped MFMA1: pa shared across both lt -> 16 ds_read_b128 (was 32)
        f32x4 S0[4], S1[4];
        #pragma unroll
        for (int mt = 0; mt < 4; ++mt) { S0[mt] = f32x4{0.f,0.f,0.f,0.f}; S1[mt] = f32x4{0.f,0.f,0.f,0.f}; }
        #pragma unroll
        for (int ks = 0; ks < 4; ++ks)
            #pragma unroll
            for (int mt = 0; mt < 4; ++mt) {
                const bf16x8 pa = ld8(&pcur[(mt * 16 + lx) * DIM + (((ks * 4 + quad) ^ lx) * 8)]);
                S0[mt] = __builtin_amdgcn_mfma_f32_16x16x32_bf16(pa, qa[0][ks], S0[mt], 0, 0, 0);
                S1[mt] = __builtin_amdgcn_mfma_f32_16x16x32_bf16(pa, qa[1][ks], S1[mt], 0, 0, 0);
            }

        // exp + pack + fused D from the same bf16 values (sKs reads are
        // quad-uniform -> LDS broadcast, conflict-free)
        #pragma unroll
        for (int mt = 0; mt < 4; ++mt) {
            const float4 kv = *reinterpret_cast<const float4*>(&sKs[m0 + mt * 16 + quad * 4]);
            ushort4 h0;
            h0.x = f2b(__expf(S0[mt][0])); h0.y = f2b(__expf(S0[mt][1]));
            h0.z = f2b(__expf(S0[mt][2])); h0.w = f2b(__expf(S0[mt][3]));
            d0 += b2f(h0.x) * kv.x + b2f(h0.y) * kv.y + b2f(h0.z) * kv.z + b2f(h0.w) * kv.w;
            *reinterpret_cast<ushort4*>(&sPhi[(wave * 32 + lx) * LDSW2 + mt * 16 + quad * 4]) = h0;
            ushort4 h1;
            h1.x = f2b(__expf(S1[mt][0])); h1.y = f2b(__expf(S1[mt][1]));
            h1.z = f2b(__expf(S1[mt][2])); h1.w = f2b(__expf(S1[mt][3]));
            d1 += b2f(h1.x) * kv.x + b2f(h1.y) * kv.y + b2f(h1.z) * kv.z + b2f(h1.w) * kv.w;
            *reinterpret_cast<ushort4*>(&sPhi[(wave * 32 + 16 + lx) * LDSW2 + mt * 16 + quad * 4]) = h1;
        }
        __syncthreads();   // sPhi visible; drains vmcnt -> sCtx + next sProj ready

        // MFMA2: out[l(32/wave), e(128)] += phi_q . ctx ; B-frags from swizzled sCtx
        #pragma unroll
        for (int ks = 0; ks < 2; ++ks) {
            const bf16x8 pa0 = ld8(&sPhi[(wave * 32 + lx) * LDSW2 + ks * 32 + quad * 8]);
            const bf16x8 pa1 = ld8(&sPhi[(wave * 32 + 16 + lx) * LDSW2 + ks * 32 + quad * 8]);
            #pragma unroll
            for (int et = 0; et < 8; ++et) {
                const bf16x8 cb = ld8(&sCtx[(et * 16 + lx) * 64 + (((ks * 4 + quad) ^ (lx & 7)) * 8)]);
                oacc[0][et] = __builtin_amdgcn_mfma_f32_16x16x32_bf16(pa0, cb, oacc[0][et], 0, 0, 0);
                oacc[1][et] = __builtin_amdgcn_mfma_f32_16x16x32_bf16(pa1, cb, oacc[1][et], 0, 0, 0);
            }
        }
    }

    // D: quad-reduce in-register, one slot per l-row
    d0 += __shfl_xor(d0, 16); d0 += __shfl_xor(d0, 32);
    d1 += __shfl_xor(d1, 16); d1 += __shfl_xor(d1, 32);
    if (quad == 0) {
        sDred[wave * 32 + lx] = d0;
        sDred[wave * 32 + 16 + lx] = d1;
    }
    __syncthreads();
    #pragma unroll
    for (int lt = 0; lt < 2; ++lt)
        #pragma unroll
        for (int r = 0; r < 4; ++r) {
            const int lrow = wave * 32 + lt * 16 + quad * 4 + r;
            const float inv = 1.0f / sDred[lrow];
            float* ob = out + ((size_t)bh * LSEQ + l0 + lrow) * DIM;
            #pragma unroll
            for (int et = 0; et < 8; ++et)
                ob[et * 16 + lx] = oacc[lt][et][r] * inv;
        }
}

extern "C" void kernel_launch(void* const* d_in, const int* in_sizes, int n_in,
                              void* d_out, int out_size, void* d_ws, size_t ws_size,
                              hipStream_t stream)
{
    (void)in_sizes; (void)n_in; (void)out_size;
    const float* q = (const float*)d_in[0];
    const float* k = (const float*)d_in[1];
    const float* v = (const float*)d_in[2];
    const float* proj = (const float*)d_in[3];
    float* out = (float*)d_out;
    char* ws = (char*)d_ws;

    // ws layout (bytes):
    //   kb     @ 0          33,554,432
    //   vt     @ 33,554,432 33,554,432   (dead after k1; ctxb aliases here in MODE 0)
    //   projb  @ 67,108,864    163,840
    //   gk     @ 67,272,704    262,144   (fp16)
    //   ksum4  @ 67,534,848    327,680
    //   ctx4   @ 67,862,528  41,943,040 fp32 (MODE 0) | 20,971,520 bf16 (MODE 1, ctxb in-place)
    unsigned short* kb    = (unsigned short*)(ws);
    unsigned short* vt    = (unsigned short*)(ws + 33554432);
    unsigned short* projb = (unsigned short*)(ws + 67108864);
    unsigned short* gk    = (unsigned short*)(ws + 67272704);
    float*          ksum4 = (float*)         (ws + 67534848);
    char*           ctx4  = ws + 67862528;

    const bool modeA = (ws_size >= 109805568u);   // fp32 partials fit?
    unsigned short* ctxb = modeA ? (unsigned short*)(ws + 33554432)   // alias over dead vt
                                 : (unsigned short*)ctx4;             // in-place over partial 0

    const float s = 0.2973017787506803f;  // 1/128^0.25

    prep_rows<<<16384, 256, 0, stream>>>(k, kb, gk, BH * LSEQ, s);
    prep_rows<<<80, 256, 0, stream>>>(proj, projb, nullptr, MFEAT, 1.0f);
    prep_vt_k<<<BH * 64, 256, 0, stream>>>(v, vt);
    if (modeA) {
        k1_ctx<0><<<640, 256, 0, stream>>>(kb, gk, projb, vt, ctx4, ksum4);
        k_cvt<0><<<2560, 256, 0, stream>>>((const float*)ctx4, nullptr, ctxb);
    } else {
        k1_ctx<1><<<640, 256, 0, stream>>>(kb, gk, projb, vt, ctx4, ksum4);
        k_cvt<1><<<2560, 256, 0, stream>>>(nullptr, (const unsigned short*)ctx4, ctxb);
    }
    k2_out<<<1024, 256, 0, stream>>>(q, projb, ctxb, ksum4, out, s);
}

// Round 9
// 362.733 us; speedup vs baseline: 1.0409x; 1.0061x over previous
//
#include <hip/hip_runtime.h>

// FAVOR+ attention, B=8 H=4 L=4096 D=128 M=640, fp32 in/out.
// out = (phi_q @ ctx) / (phi_q @ ksum); exp(eps)/sqrt(M) and per-row e^{-g_q}
// cancel in the ratio.
// R11: prep_rows(k) FUSED into k1 (k loaded fp32 direct, scaled+converted
// in-reg like k2 does for q; g computed in-reg via quad shfl-reduce -> sG).
// Eliminates a ~400MB-traffic prep kernel (~40-65us). kb/gk removed from ws.
// k1 compute structure + k2 = R10 (pfr/pa shared across lt, reg ksum/D).

#define BH 32
#define LSEQ 4096
#define DIM 128
#define MFEAT 640
#define LDSW 136   // k1 padded row stride (elements); 272 B rows
#define LDSW2 72   // k2 padded row stride for 64-wide sPhi; 144 B rows

typedef __bf16 bf16x8 __attribute__((ext_vector_type(8)));
typedef float f32x4 __attribute__((ext_vector_type(4)));

__device__ __forceinline__ unsigned short f2b(float f) {
    union { float f; unsigned u; } c; c.f = f;
    unsigned u = c.u + 0x7FFFu + ((c.u >> 16) & 1u);   // RNE bf16 (finite inputs only)
    return (unsigned short)(u >> 16);
}
__device__ __forceinline__ float b2f(unsigned short h) {
    union { unsigned u; float f; } c; c.u = ((unsigned)h) << 16;
    return c.f;
}
__device__ __forceinline__ bf16x8 ld8(const unsigned short* p) {
    union { uint4 q; bf16x8 v; } c;
    c.q = *reinterpret_cast<const uint4*>(p);
    return c.v;
}
// async global->LDS, 16 B per lane; LDS dest = uniform base + lane*16
__device__ __forceinline__ void gl_lds16(const unsigned short* g, unsigned short* l) {
    __builtin_amdgcn_global_load_lds(
        (const __attribute__((address_space(1))) void*)g,
        (__attribute__((address_space(3))) void*)l, 16, 0, 0);
}

// ---------------- prep: rows of 128 fp32 -> bf16 (proj only now) ----------------
__global__ void prep_rows(const float* __restrict__ src, unsigned short* __restrict__ dst,
                          int nrows, float scale)
{
    const int row = blockIdx.x * 8 + (threadIdx.x >> 5);
    const int ln = threadIdx.x & 31;
    if (row >= nrows) return;
    const float4 f = *reinterpret_cast<const float4*>(src + (size_t)row * DIM + ln * 4);
    ushort4 o; o.x = f2b(f.x * scale); o.y = f2b(f.y * scale);
    o.z = f2b(f.z * scale); o.w = f2b(f.w * scale);
    *reinterpret_cast<ushort4*>(dst + (size_t)row * DIM + ln * 4) = o;
}

// ---------------- prep: v [bh][l][e] fp32 -> vt [bh][e][l] bf16 ----------------
__global__ void prep_vt_k(const float* __restrict__ v, unsigned short* __restrict__ vt)
{
    __shared__ float tile[64][129];
    const int bh = blockIdx.x >> 6;
    const int l0 = (blockIdx.x & 63) * 64;
    const int tid = threadIdx.x;
    const float* vb = v + ((size_t)bh * LSEQ + l0) * DIM;
    for (int u = tid; u < 2048; u += 256) {
        const int r = u >> 5, c = (u & 31) * 4;
        const float4 f = *reinterpret_cast<const float4*>(vb + (size_t)r * DIM + c);
        tile[r][c] = f.x; tile[r][c + 1] = f.y; tile[r][c + 2] = f.z; tile[r][c + 3] = f.w;
    }
    __syncthreads();
    const int e = tid >> 1, hf = tid & 1;
    unsigned w[16];
    #pragma unroll
    for (int j = 0; j < 16; ++j) {
        w[j] = ((unsigned)f2b(tile[hf * 32 + 2 * j][e])) |
               (((unsigned)f2b(tile[hf * 32 + 2 * j + 1][e])) << 16);
    }
    unsigned short* dst = vt + ((size_t)bh * DIM + e) * LSEQ + l0 + hf * 32;
    uint4* d4 = reinterpret_cast<uint4*>(dst);
    d4[0] = make_uint4(w[0], w[1], w[2], w[3]);
    d4[1] = make_uint4(w[4], w[5], w[6], w[7]);
    d4[2] = make_uint4(w[8], w[9], w[10], w[11]);
    d4[3] = make_uint4(w[12], w[13], w[14], w[15]);
}

// ---------------- kernel 1: per-part ctx partials [part][bh][e][m] + ksum4 ----------------
// MODE 0: fp32 partials; MODE 1: bf16 partials (ws-constrained fallback)
// k loaded fp32 direct (no kb prep); g computed in-reg -> sG.
template<int MODE>
__global__ __launch_bounds__(256, 2) void k1_ctx(
    const float* __restrict__ kf, const unsigned short* __restrict__ projb,
    const unsigned short* __restrict__ vt,
    void* __restrict__ ctx4, float* __restrict__ ksum4, float scale)
{
    __shared__ __align__(16) unsigned short sProj[128 * LDSW];
    __shared__ __align__(16) unsigned short sPhi[128 * LDSW];  // [m][l]
    __shared__ float sG[128];
    __shared__ float sKred[512];

    const int tid = threadIdx.x;
    const int wave = tid >> 6, lane = tid & 63;
    const int quad = lane >> 4, lx = lane & 15;

    // XCD swizzle: same-bh blocks land on same XCD
    const int xcd = blockIdx.x & 7;
    const int kk = blockIdx.x >> 3;           // 0..79
    const int bh = xcd * 4 + kk / 20;
    const int t20 = kk % 20;
    const int part = t20 / 5;                 // L split 0..3
    const int mc = t20 % 5;                   // m-chunk 0..4 (128 each)
    const int m0 = mc * 128;
    const int lbase = part * 1024;

    // stage proj chunk once per block
    for (int u = tid; u < 128 * 16; u += 256) {
        const int r = u >> 4, c = (u & 15) * 8;
        *reinterpret_cast<uint4*>(&sProj[r * LDSW + c]) =
            *reinterpret_cast<const uint4*>(projb + (size_t)(m0 + r) * DIM + c);
    }

    f32x4 acc[8][2];
    #pragma unroll
    for (int i = 0; i < 8; ++i)
        #pragma unroll
        for (int j = 0; j < 2; ++j) acc[i][j] = f32x4{0.f, 0.f, 0.f, 0.f};
    float ksr[8];
    #pragma unroll
    for (int i = 0; i < 8; ++i) ksr[i] = 0.f;

    const float* kfb = kf + (size_t)bh * LSEQ * DIM;
    const unsigned short* vbase = vt + (size_t)bh * (DIM * LSEQ);

    #pragma unroll 1
    for (int tile = 0; tile < 8; ++tile) {
        const int l0 = lbase + tile * 128;

        // k A-frags: fp32 direct load, scale+convert in-reg; row sum-of-squares
        // for g (lane (quad,lx) owns row lt*16+lx; quads hold disjoint columns)
        bf16x8 afr[2][4];
        float ssl0 = 0.f, ssl1 = 0.f;
        #pragma unroll
        for (int lt = 0; lt < 2; ++lt)
            #pragma unroll
            for (int ks = 0; ks < 4; ++ks) {
                const float* p = kfb + (size_t)(l0 + wave * 32 + lt * 16 + lx) * DIM + ks * 32 + quad * 8;
                const float4 f0 = *reinterpret_cast<const float4*>(p);
                const float4 f1 = *reinterpret_cast<const float4*>(p + 4);
                const float a0 = f0.x * scale, a1 = f0.y * scale, a2 = f0.z * scale, a3 = f0.w * scale;
                const float a4 = f1.x * scale, a5 = f1.y * scale, a6 = f1.z * scale, a7 = f1.w * scale;
                const float sq = a0*a0 + a1*a1 + a2*a2 + a3*a3 + a4*a4 + a5*a5 + a6*a6 + a7*a7;
                if (lt == 0) ssl0 += sq; else ssl1 += sq;
                union { unsigned u[4]; bf16x8 v; } c;
                c.u[0] = ((unsigned)f2b(a0)) | (((unsigned)f2b(a1)) << 16);
                c.u[1] = ((unsigned)f2b(a2)) | (((unsigned)f2b(a3)) << 16);
                c.u[2] = ((unsigned)f2b(a4)) | (((unsigned)f2b(a5)) << 16);
                c.u[3] = ((unsigned)f2b(a6)) | (((unsigned)f2b(a7)) << 16);
                afr[lt][ks] = c.v;
            }
        // reduce over quads -> full row sum; write g to sG (rows wave*32+lt*16+lx)
        ssl0 += __shfl_xor(ssl0, 16); ssl0 += __shfl_xor(ssl0, 32);
        ssl1 += __shfl_xor(ssl1, 16); ssl1 += __shfl_xor(ssl1, 32);
        if (quad == 0) {
            sG[wave * 32 + lx] = 0.5f * ssl0;
            sG[wave * 32 + 16 + lx] = 0.5f * ssl1;
        }

        __syncthreads();   // prev tile's sPhi readers done; sG (and sProj on t0) visible

        // MFMA1: pfr shared across both lt -> 32 ds_read_b128
        f32x4 S0[8], S1[8];
        #pragma unroll
        for (int mt = 0; mt < 8; ++mt) { S0[mt] = f32x4{0.f,0.f,0.f,0.f}; S1[mt] = f32x4{0.f,0.f,0.f,0.f}; }
        #pragma unroll
        for (int ks = 0; ks < 4; ++ks)
            #pragma unroll
            for (int mt = 0; mt < 8; ++mt) {
                const bf16x8 pfr = ld8(&sProj[(mt * 16 + lx) * LDSW + ks * 32 + quad * 8]);
                S0[mt] = __builtin_amdgcn_mfma_f32_16x16x32_bf16(afr[0][ks], pfr, S0[mt], 0, 0, 0);
                S1[mt] = __builtin_amdgcn_mfma_f32_16x16x32_bf16(afr[1][ks], pfr, S1[mt], 0, 0, 0);
            }

        // exp + pack + register ksum (identical bf16 values as the MFMA consumes)
        {
            const float4 g0 = *reinterpret_cast<const float4*>(&sG[wave * 32 + quad * 4]);
            const float4 g1 = *reinterpret_cast<const float4*>(&sG[wave * 32 + 16 + quad * 4]);
            #pragma unroll
            for (int mt = 0; mt < 8; ++mt) {
                ushort4 h0;
                h0.x = f2b(__expf(S0[mt][0] - g0.x)); h0.y = f2b(__expf(S0[mt][1] - g0.y));
                h0.z = f2b(__expf(S0[mt][2] - g0.z)); h0.w = f2b(__expf(S0[mt][3] - g0.w));
                ksr[mt] += b2f(h0.x) + b2f(h0.y) + b2f(h0.z) + b2f(h0.w);
                *reinterpret_cast<ushort4*>(&sPhi[(mt * 16 + lx) * LDSW + wave * 32 + quad * 4]) = h0;
                ushort4 h1;
                h1.x = f2b(__expf(S1[mt][0] - g1.x)); h1.y = f2b(__expf(S1[mt][1] - g1.y));
                h1.z = f2b(__expf(S1[mt][2] - g1.z)); h1.w = f2b(__expf(S1[mt][3] - g1.w));
                ksr[mt] += b2f(h1.x) + b2f(h1.y) + b2f(h1.z) + b2f(h1.w);
                *reinterpret_cast<ushort4*>(&sPhi[(mt * 16 + lx) * LDSW + wave * 32 + 16 + quad * 4]) = h1;
            }
        }

        // vt B-frags issued BEFORE barrier: latency drains at the barrier
        bf16x8 vfr0[4], vfr1[4];
        #pragma unroll
        for (int ks = 0; ks < 4; ++ks) {
            vfr0[ks] = ld8(vbase + (size_t)(wave * 32 + lx) * LSEQ + l0 + ks * 32 + quad * 8);
            vfr1[ks] = ld8(vbase + (size_t)(wave * 32 + 16 + lx) * LSEQ + l0 + ks * 32 + quad * 8);
        }
        __syncthreads();   // sPhi visible; vfr drained

        // MFMA2: ctx[m(128), e(32/wave)] += phi^T . v  (16 independent chains)
        #pragma unroll
        for (int ks = 0; ks < 4; ++ks) {
            #pragma unroll
            for (int mt = 0; mt < 8; ++mt) {
                const bf16x8 afr2 = ld8(&sPhi[(mt * 16 + lx) * LDSW + ks * 32 + quad * 8]);
                acc[mt][0] = __builtin_amdgcn_mfma_f32_16x16x32_bf16(afr2, vfr0[ks], acc[mt][0], 0, 0, 0);
                acc[mt][1] = __builtin_amdgcn_mfma_f32_16x16x32_bf16(afr2, vfr1[ks], acc[mt][1], 0, 0, 0);
            }
        }
    }

    // plain transposed stores: ctx4[part][bh][e][m]; lane holds 4 consecutive m
    #pragma unroll
    for (int mt = 0; mt < 8; ++mt)
        #pragma unroll
        for (int j = 0; j < 2; ++j) {
            const int e = wave * 32 + j * 16 + lx;
            const size_t off = (((size_t)part * BH + bh) * DIM + e) * MFEAT + m0 + mt * 16 + quad * 4;
            if (MODE == 0) {
                float4 st; st.x = acc[mt][j][0]; st.y = acc[mt][j][1]; st.z = acc[mt][j][2]; st.w = acc[mt][j][3];
                *reinterpret_cast<float4*>((float*)ctx4 + off) = st;
            } else {
                ushort4 st; st.x = f2b(acc[mt][j][0]); st.y = f2b(acc[mt][j][1]);
                st.z = f2b(acc[mt][j][2]); st.w = f2b(acc[mt][j][3]);
                *reinterpret_cast<ushort4*>((unsigned short*)ctx4 + off) = st;
            }
        }

    // ksum: quad-reduce in-register, then cross-wave via small LDS
    #pragma unroll
    for (int mt = 0; mt < 8; ++mt) {
        ksr[mt] += __shfl_xor(ksr[mt], 16);
        ksr[mt] += __shfl_xor(ksr[mt], 32);
    }
    if (quad == 0) {
        #pragma unroll
        for (int mt = 0; mt < 8; ++mt)
            sKred[wave * 128 + mt * 16 + lx] = ksr[mt];
    }
    __syncthreads();
    if (tid < 128)
        ksum4[((size_t)part * BH + bh) * MFEAT + m0 + tid] =
            sKred[tid] + sKred[128 + tid] + sKred[256 + tid] + sKred[384 + tid];
}

// ---------------- cvt: sum 4 partials -> ctxb bf16 [bh][e][m] (elementwise) ----------------
#define PELEM (size_t)(BH * DIM * MFEAT)   // 2,621,440 per partial
template<int MODE>
__global__ void k_cvt(const float* __restrict__ pf, const unsigned short* __restrict__ ph,
                      unsigned short* __restrict__ ctxb)
{
    const size_t base = ((size_t)blockIdx.x * 256 + threadIdx.x) * 4;
    float s0, s1, s2, s3;
    if (MODE == 0) {
        float4 a = *reinterpret_cast<const float4*>(pf + base);
        float4 b = *reinterpret_cast<const float4*>(pf + PELEM + base);
        float4 c = *reinterpret_cast<const float4*>(pf + 2 * PELEM + base);
        float4 d = *reinterpret_cast<const float4*>(pf + 3 * PELEM + base);
        s0 = a.x + b.x + c.x + d.x; s1 = a.y + b.y + c.y + d.y;
        s2 = a.z + b.z + c.z + d.z; s3 = a.w + b.w + c.w + d.w;
    } else {
        ushort4 a = *reinterpret_cast<const ushort4*>(ph + base);
        ushort4 b = *reinterpret_cast<const ushort4*>(ph + PELEM + base);
        ushort4 c = *reinterpret_cast<const ushort4*>(ph + 2 * PELEM + base);
        ushort4 d = *reinterpret_cast<const ushort4*>(ph + 3 * PELEM + base);
        s0 = b2f(a.x) + b2f(b.x) + b2f(c.x) + b2f(d.x);
        s1 = b2f(a.y) + b2f(b.y) + b2f(c.y) + b2f(d.y);
        s2 = b2f(a.z) + b2f(b.z) + b2f(c.z) + b2f(d.z);
        s3 = b2f(a.w) + b2f(b.w) + b2f(c.w) + b2f(d.w);
    }
    ushort4 o; o.x = f2b(s0); o.y = f2b(s1); o.z = f2b(s2); o.w = f2b(s3);
    *reinterpret_cast<ushort4*>(ctxb + base) = o;   // MODE 1: in-place over partial 0 (own slot)
}

// ---------------- kernel 2: out = (phi_q @ ctx) / (phi_q @ ksum) ----------------
// 128-row tiles, grid 1024, XCD swizzle. m-chunk 64. ALL MFMA operands LDS-fed:
// sProj double-buffered, sCtx staged during MFMA1. pa shared across lt; D fused
// into the pack from registers (no separate D-pass).
__global__ __launch_bounds__(256, 2) void k2_out(
    const float* __restrict__ q, const unsigned short* __restrict__ projb,
    const unsigned short* __restrict__ ctxb, const float* __restrict__ ksum4,
    float* __restrict__ out, float scale)
{
    __shared__ __align__(16) unsigned short sPhi[128 * LDSW2];   // [l][m] padded
    __shared__ __align__(16) unsigned short sCtx[128 * 64];      // swizzled [e][g^e]
    __shared__ __align__(16) unsigned short sProj[2][64 * DIM];  // dbuf swizzled [m][g^m]
    __shared__ float sKs[MFEAT];
    __shared__ float sDred[128];

    const int tid = threadIdx.x;
    const int wave = tid >> 6, lane = tid & 63;
    const int quad = lane >> 4, lx = lane & 15;

    // XCD swizzle: 32 blocks per bh share one XCD (ctxb[bh] stays L2-hot)
    const int xcd = blockIdx.x & 7;
    const int kk = blockIdx.x >> 3;           // 0..127
    const int bh = xcd * 4 + (kk >> 5);
    const int l0 = (kk & 31) * 128;

    // prologue: stage proj chunk 0 (async; drained by first barrier)
    {
        const int j = lane & 15;
        #pragma unroll
        for (int i = 0; i < 4; ++i) {
            const int r = wave * 16 + i * 4 + (lane >> 4);
            const int g = j ^ (r & 15);
            gl_lds16(projb + (size_t)r * DIM + g * 8,
                     &sProj[0][(wave * 16 + i * 4) * DIM]);
        }
    }

    for (int i = tid; i < MFEAT; i += 256)
        sKs[i] = ksum4[(size_t)bh * MFEAT + i]
               + ksum4[(size_t)(BH + bh) * MFEAT + i]
               + ksum4[(size_t)(2 * BH + bh) * MFEAT + i]
               + ksum4[(size_t)(3 * BH + bh) * MFEAT + i];

    // q frags: fp32 -> scaled bf16 in-reg (32 VGPR), B-operand of swapped MFMA1
    bf16x8 qa[2][4];
    #pragma unroll
    for (int lt = 0; lt < 2; ++lt)
        #pragma unroll
        for (int ks = 0; ks < 4; ++ks) {
            const float* p = q + ((size_t)bh * LSEQ + l0 + wave * 32 + lt * 16 + lx) * DIM + ks * 32 + quad * 8;
            const float4 f0 = *reinterpret_cast<const float4*>(p);
            const float4 f1 = *reinterpret_cast<const float4*>(p + 4);
            union { unsigned u[4]; bf16x8 v; } c;
            c.u[0] = ((unsigned)f2b(f0.x * scale)) | (((unsigned)f2b(f0.y * scale)) << 16);
            c.u[1] = ((unsigned)f2b(f0.z * scale)) | (((unsigned)f2b(f0.w * scale)) << 16);
            c.u[2] = ((unsigned)f2b(f1.x * scale)) | (((unsigned)f2b(f1.y * scale)) << 16);
            c.u[3] = ((unsigned)f2b(f1.z * scale)) | (((unsigned)f2b(f1.w * scale)) << 16);
            qa[lt][ks] = c.v;
        }

    f32x4 oacc[2][8];
    #pragma unroll
    for (int i = 0; i < 2; ++i)
        #pragma unroll
        for (int j = 0; j < 8; ++j) oacc[i][j] = f32x4{0.f, 0.f, 0.f, 0.f};
    float d0 = 0.f, d1 = 0.f;

    const unsigned short* cbase = ctxb + (size_t)bh * DIM * MFEAT;

    #pragma unroll 1
    for (int ch = 0; ch < 10; ++ch) {
        const int m0 = ch * 64;
        const unsigned short* pcur = sProj[ch & 1];
        __syncthreads();   // prev readers done; drains staging -> sProj[cur] ready

        // async-stage ctx tile [128 e][64 m] for THIS chunk (consumed after barrier B)
        {
            const int jj = lane & 7;
            const int rsub = lane >> 3;
            #pragma unroll
            for (int i = 0; i < 4; ++i) {
                const int r = wave * 32 + i * 8 + rsub;
                const int g = jj ^ (r & 7);
                gl_lds16(cbase + (size_t)r * MFEAT + m0 + g * 8,
                         &sCtx[(wave * 32 + i * 8) * 64]);
            }
        }
        // async-stage proj chunk ch+1 into the other buffer (consumed next iter)
        if (ch < 9) {
            unsigned short* pnxt = sProj[(ch & 1) ^ 1];
            const int j = lane & 15;
            #pragma unroll
            for (int i = 0; i < 4; ++i) {
                const int r = wave * 16 + i * 4 + (lane >> 4);
                const int g = j ^ (r & 15);
                gl_lds16(projb + (size_t)(m0 + 64 + r) * DIM + g * 8,
                         &pnxt[(wave * 16 + i * 4) * DIM]);
            }
        }

        // swapped MFMA1: pa shared across both lt -> 16 ds_read_b128
        f32x4 S0[4], S1[4];
        #pragma unroll
        for (int mt = 0; mt < 4; ++mt) { S0[mt] = f32x4{0.f,0.f,0.f,0.f}; S1[mt] = f32x4{0.f,0.f,0.f,0.f}; }
        #pragma unroll
        for (int ks = 0; ks < 4; ++ks)
            #pragma unroll
            for (int mt = 0; mt < 4; ++mt) {
                const bf16x8 pa = ld8(&pcur[(mt * 16 + lx) * DIM + (((ks * 4 + quad) ^ lx) * 8)]);
                S0[mt] = __builtin_amdgcn_mfma_f32_16x16x32_bf16(pa, qa[0][ks], S0[mt], 0, 0, 0);
                S1[mt] = __builtin_amdgcn_mfma_f32_16x16x32_bf16(pa, qa[1][ks], S1[mt], 0, 0, 0);
            }

        // exp + pack + fused D from the same bf16 values (sKs reads quad-uniform)
        #pragma unroll
        for (int mt = 0; mt < 4; ++mt) {
            const float4 kv = *reinterpret_cast<const float4*>(&sKs[m0 + mt * 16 + quad * 4]);
            ushort4 h0;
            h0.x = f2b(__expf(S0[mt][0])); h0.y = f2b(__expf(S0[mt][1]));
            h0.z = f2b(__expf(S0[mt][2])); h0.w = f2b(__expf(S0[mt][3]));
            d0 += b2f(h0.x) * kv.x + b2f(h0.y) * kv.y + b2f(h0.z) * kv.z + b2f(h0.w) * kv.w;
            *reinterpret_cast<ushort4*>(&sPhi[(wave * 32 + lx) * LDSW2 + mt * 16 + quad * 4]) = h0;
            ushort4 h1;
            h1.x = f2b(__expf(S1[mt][0])); h1.y = f2b(__expf(S1[mt][1]));
            h1.z = f2b(__expf(S1[mt][2])); h1.w = f2b(__expf(S1[mt][3]));
            d1 += b2f(h1.x) * kv.x + b2f(h1.y) * kv.y + b2f(h1.z) * kv.z + b2f(h1.w) * kv.w;
            *reinterpret_cast<ushort4*>(&sPhi[(wave * 32 + 16 + lx) * LDSW2 + mt * 16 + quad * 4]) = h1;
        }
        __syncthreads();   // sPhi visible; drains vmcnt -> sCtx + next sProj ready

        // MFMA2: out[l(32/wave), e(128)] += phi_q . ctx ; B-frags from swizzled sCtx
        #pragma unroll
        for (int ks = 0; ks < 2; ++ks) {
            const bf16x8 pa0 = ld8(&sPhi[(wave * 32 + lx) * LDSW2 + ks * 32 + quad * 8]);
            const bf16x8 pa1 = ld8(&sPhi[(wave * 32 + 16 + lx) * LDSW2 + ks * 32 + quad * 8]);
            #pragma unroll
            for (int et = 0; et < 8; ++et) {
                const bf16x8 cb = ld8(&sCtx[(et * 16 + lx) * 64 + (((ks * 4 + quad) ^ (lx & 7)) * 8)]);
                oacc[0][et] = __builtin_amdgcn_mfma_f32_16x16x32_bf16(pa0, cb, oacc[0][et], 0, 0, 0);
                oacc[1][et] = __builtin_amdgcn_mfma_f32_16x16x32_bf16(pa1, cb, oacc[1][et], 0, 0, 0);
            }
        }
    }

    // D: quad-reduce in-register, one slot per l-row
    d0 += __shfl_xor(d0, 16); d0 += __shfl_xor(d0, 32);
    d1 += __shfl_xor(d1, 16); d1 += __shfl_xor(d1, 32);
    if (quad == 0) {
        sDred[wave * 32 + lx] = d0;
        sDred[wave * 32 + 16 + lx] = d1;
    }
    __syncthreads();
    #pragma unroll
    for (int lt = 0; lt < 2; ++lt)
        #pragma unroll
        for (int r = 0; r < 4; ++r) {
            const int lrow = wave * 32 + lt * 16 + quad * 4 + r;
            const float inv = 1.0f / sDred[lrow];
            float* ob = out + ((size_t)bh * LSEQ + l0 + lrow) * DIM;
            #pragma unroll
            for (int et = 0; et < 8; ++et)
                ob[et * 16 + lx] = oacc[lt][et][r] * inv;
        }
}

extern "C" void kernel_launch(void* const* d_in, const int* in_sizes, int n_in,
                              void* d_out, int out_size, void* d_ws, size_t ws_size,
                              hipStream_t stream)
{
    (void)in_sizes; (void)n_in; (void)out_size;
    const float* q = (const float*)d_in[0];
    const float* k = (const float*)d_in[1];
    const float* v = (const float*)d_in[2];
    const float* proj = (const float*)d_in[3];
    float* out = (float*)d_out;
    char* ws = (char*)d_ws;

    // ws layout (bytes) — kb/gk slots no longer used (k read fp32 direct):
    //   (free) @ 0          33,554,432
    //   vt     @ 33,554,432 33,554,432   (dead after k1; ctxb aliases here in MODE 0)
    //   projb  @ 67,108,864    163,840
    //   (free) @ 67,272,704    262,144
    //   ksum4  @ 67,534,848    327,680
    //   ctx4   @ 67,862,528  41,943,040 fp32 (MODE 0) | 20,971,520 bf16 (MODE 1, ctxb in-place)
    unsigned short* vt    = (unsigned short*)(ws + 33554432);
    unsigned short* projb = (unsigned short*)(ws + 67108864);
    float*          ksum4 = (float*)         (ws + 67534848);
    char*           ctx4  = ws + 67862528;

    const bool modeA = (ws_size >= 109805568u);   // fp32 partials fit?
    unsigned short* ctxb = modeA ? (unsigned short*)(ws + 33554432)   // alias over dead vt
                                 : (unsigned short*)ctx4;             // in-place over partial 0

    const float s = 0.2973017787506803f;  // 1/128^0.25

    prep_rows<<<80, 256, 0, stream>>>(proj, projb, MFEAT, 1.0f);
    prep_vt_k<<<BH * 64, 256, 0, stream>>>(v, vt);
    if (modeA) {
        k1_ctx<0><<<640, 256, 0, stream>>>(k, projb, vt, ctx4, ksum4, s);
        k_cvt<0><<<2560, 256, 0, stream>>>((const float*)ctx4, nullptr, ctxb);
    } else {
        k1_ctx<1><<<640, 256, 0, stream>>>(k, projb, vt, ctx4, ksum4, s);
        k_cvt<1><<<2560, 256, 0, stream>>>(nullptr, (const unsigned short*)ctx4, ctxb);
    }
    k2_out<<<1024, 256, 0, stream>>>(q, projb, ctxb, ksum4, out, s);
}